// Round 9
// baseline (285.138 us; speedup 1.0000x reference)
//
#include <hip/hip_runtime.h>
#include <hip/hip_bf16.h>
#include <math.h>

// B=2, S=2048, D=1024, H=16, HD=64. Inputs fp32, output fp32.
// R9: flash attention restructured — NO LDS staging for K/V, no in-loop
// barriers. Each wave loads K/V MFMA fragments directly from global
// (16B contiguous in the [B,H,S,HD] / [B,H,HD,S] layouts), register-
// prefetched one tile ahead. Waves fully independent; XCD-aware bh
// swizzle keeps per-XCD K/V working set L2-resident. PT round-trip
// (wave-private, 5 KB LDS) is the only LDS use. Deferred l-reduction.
// GEMMs (m97-style bf16 MFMA, fused QKV) unchanged from R7/R8.

#define Bdim  2
#define Sdim  2048
#define Ddim  1024
#define Hn    16
#define HDdim 64
#define Mdim  (Bdim * Sdim)   // 4096

typedef unsigned short ushort_t;
typedef __attribute__((ext_vector_type(8))) short bfrag;   // 8 bf16 (4 VGPR)
typedef __attribute__((ext_vector_type(4))) float f4;

__device__ __forceinline__ ushort_t f2bf(float f) {
    union { float f; unsigned int i; } c;
    c.f = f;
    unsigned int x = c.i;
    unsigned int r = (x + 0x7fffu + ((x >> 16) & 1u)) >> 16;  // RNE
    return (ushort_t)r;
}

__device__ __forceinline__ void glds16(const void* g, void* l) {
    __builtin_amdgcn_global_load_lds(
        (const __attribute__((address_space(1))) unsigned int*)g,
        (__attribute__((address_space(3))) unsigned int*)l, 16, 0, 0);
}

// ---------------- cast x: fp32 [M][K] -> bf16 same layout ----------------
__global__ __launch_bounds__(256)
void cast_x(const float* __restrict__ x, ushort_t* __restrict__ xb)
{
    size_t i = ((size_t)blockIdx.x * 256 + threadIdx.x) * 8;
    float4 a = *(const float4*)(x + i);
    float4 b = *(const float4*)(x + i + 4);
    ushort_t o[8] = {f2bf(a.x), f2bf(a.y), f2bf(a.z), f2bf(a.w),
                     f2bf(b.x), f2bf(b.y), f2bf(b.z), f2bf(b.w)};
    *(bfrag*)(xb + i) = *(const bfrag*)o;
}

// ------------- transpose-cast weights: W[k][n] fp32 -> Wt[n][k] bf16 -------
__global__ __launch_bounds__(256)
void wtrans(const float* __restrict__ W0, const float* __restrict__ W1,
            const float* __restrict__ W2, const float* __restrict__ W3,
            ushort_t* __restrict__ qkvT, ushort_t* __restrict__ oT)
{
    __shared__ ushort_t t[64][72];   // [n][k], padded
    const int tid = threadIdx.x;
    const int z = blockIdx.z;
    const float* W = (z == 0) ? W0 : (z == 1) ? W1 : (z == 2) ? W2 : W3;
    const int k0 = blockIdx.y * 64, n0 = blockIdx.x * 64;

    const int r = tid >> 4, c4 = (tid & 15) * 4;
    #pragma unroll
    for (int rr = 0; rr < 4; ++rr) {
        int k = r + rr * 16;
        float4 v = *(const float4*)&W[(size_t)(k0 + k) * Ddim + n0 + c4];
        t[c4 + 0][k] = f2bf(v.x);
        t[c4 + 1][k] = f2bf(v.y);
        t[c4 + 2][k] = f2bf(v.z);
        t[c4 + 3][k] = f2bf(v.w);
    }
    __syncthreads();
    ushort_t* out = (z < 3) ? (qkvT + (size_t)z * Ddim * Ddim) : oT;
    const int n = tid >> 2, kc = (tid & 3) * 16;
    *(bfrag*)&out[(size_t)(n0 + n) * Ddim + k0 + kc] = *(const bfrag*)&t[n][kc];
    *(bfrag*)&out[(size_t)(n0 + n) * Ddim + k0 + kc + 8] = *(const bfrag*)&t[n][kc + 8];
}

// ---------------- MFMA GEMM (m97 structure, NT) ----------------
// MODE 0: Ntot=3072 fused QKV; scatter bf16 to Q,K [B,H,S,HD], Vt [B,H,HD,S].
// MODE 1: Ntot=1024; fp32 out [M,N].
template <int MODE>
__global__ __launch_bounds__(256)
void gemm_mfma(const ushort_t* __restrict__ A, const ushort_t* __restrict__ Bt,
               const float* __restrict__ bQ, const float* __restrict__ bK,
               const float* __restrict__ bV,
               ushort_t* __restrict__ oQ, ushort_t* __restrict__ oK,
               ushort_t* __restrict__ oVt, float* __restrict__ oF)
{
    __shared__ ushort_t As[128 * 32];   // [row][k], 64 B rows
    __shared__ ushort_t Bs[128 * 32];

    const int tid  = threadIdx.x;
    const int lane = tid & 63;
    const int w    = tid >> 6;
    const int l15  = lane & 15;
    const int quad = lane >> 4;
    const int wr   = w >> 1, wc = w & 1;
    const int m0 = blockIdx.y * 128;
    const int n0 = blockIdx.x * 128;

    f4 acc[4][4];
    #pragma unroll
    for (int i = 0; i < 4; ++i)
        #pragma unroll
        for (int j = 0; j < 4; ++j) acc[i][j] = (f4){0.f, 0.f, 0.f, 0.f};

    const int srow  = w * 32 + (lane >> 2);
    const int selem = (lane & 3) * 8;
    const ushort_t* gA = A  + (size_t)(m0 + srow) * Ddim + selem;
    const ushort_t* gB = Bt + (size_t)(n0 + srow) * Ddim + selem;
    char* lA0 = (char*)As + (w * 32) * 64;
    char* lB0 = (char*)Bs + (w * 32) * 64;

    for (int kk = 0; kk < Ddim; kk += 32) {
        __syncthreads();
        glds16(gA + kk,              lA0);
        glds16(gA + 16 * Ddim + kk,  lA0 + 1024);
        glds16(gB + kk,              lB0);
        glds16(gB + 16 * Ddim + kk,  lB0 + 1024);
        __syncthreads();

        bfrag Af[4], Bf[4];
        #pragma unroll
        for (int i = 0; i < 4; ++i)
            Af[i] = *(const bfrag*)&As[(wr * 64 + i * 16 + l15) * 32 + quad * 8];
        #pragma unroll
        for (int j = 0; j < 4; ++j)
            Bf[j] = *(const bfrag*)&Bs[(wc * 64 + j * 16 + l15) * 32 + quad * 8];
        #pragma unroll
        for (int i = 0; i < 4; ++i)
            #pragma unroll
            for (int j = 0; j < 4; ++j)
                acc[i][j] = __builtin_amdgcn_mfma_f32_16x16x32_bf16(Af[i], Bf[j], acc[i][j], 0, 0, 0);
    }

    if constexpr (MODE == 0) {
        const int sel   = n0 >> 10;
        const int dbase = n0 & 1023;
        const float* bias = (sel == 0) ? bQ : (sel == 1) ? bK : bV;
        ushort_t* dst = (sel == 0) ? oQ : (sel == 1) ? oK : oVt;
        #pragma unroll
        for (int j = 0; j < 4; ++j) {
            int dn = dbase + wc * 64 + j * 16 + l15;
            float bv = bias[dn];
            int h = dn >> 6, e = dn & 63;
            #pragma unroll
            for (int i = 0; i < 4; ++i) {
                #pragma unroll
                for (int r = 0; r < 4; ++r) {
                    int m = m0 + wr * 64 + i * 16 + quad * 4 + r;
                    int b = m >> 11, s = m & 2047;
                    float v = acc[i][j][r] + bv;
                    if (sel < 2)
                        dst[((((size_t)b * Hn + h) * Sdim + s) << 6) + e] = f2bf(v);
                    else
                        dst[(((size_t)b * Hn + h) * HDdim + e) * Sdim + s] = f2bf(v);
                }
            }
        }
    } else {
        #pragma unroll
        for (int j = 0; j < 4; ++j) {
            int n = n0 + wc * 64 + j * 16 + l15;
            float bv = bQ[n];   // bo
            #pragma unroll
            for (int i = 0; i < 4; ++i)
                #pragma unroll
                for (int r = 0; r < 4; ++r) {
                    int m = m0 + wr * 64 + i * 16 + quad * 4 + r;
                    oF[(size_t)m * Ddim + n] = acc[i][j][r] + bv;
                }
        }
    }
}

// ---------------- Flash attention: barrier-free, direct global frags -------
#define FA_BQ 64
#define FA_BK 32

struct FaState {
    f4 O[4];
    float m_prev;
    float l_part;
};

__device__ __forceinline__ void fa_tile(
    int kt, int ntiles, int qw, int l15, int quad, int lane,
    const ushort_t* __restrict__ Kp, const ushort_t* __restrict__ Vp,
    bfrag Qf0, bfrag Qf1,
    bfrag* curK, bfrag* curV, bfrag* nxtK, bfrag* nxtV,
    FaState& st, ushort_t* PTw)
{
    const int k0 = kt * FA_BK;
    const float scale = 0.125f;

    // prefetch next tile's K/V fragments (latency hidden by this tile)
    if (kt + 1 < ntiles) {
        const int kn0 = k0 + FA_BK;
        #pragma unroll
        for (int h = 0; h < 2; ++h) {
            const ushort_t* kr = Kp + (size_t)(kn0 + h * 16 + l15) * HDdim;
            nxtK[h * 2]     = *(const bfrag*)(kr + quad * 8);
            nxtK[h * 2 + 1] = *(const bfrag*)(kr + 32 + quad * 8);
        }
        #pragma unroll
        for (int c = 0; c < 4; ++c)
            nxtV[c] = *(const bfrag*)(Vp + (size_t)(c * 16 + l15) * Sdim + kn0 + quad * 8);
    }

    // S^T = K . Q^T  (C: row=key_loc=quad*4+r, col=q=l15)
    f4 ST[2];
    #pragma unroll
    for (int h = 0; h < 2; ++h) {
        f4 s = (f4){0.f, 0.f, 0.f, 0.f};
        s = __builtin_amdgcn_mfma_f32_16x16x32_bf16(curK[h * 2],     Qf0, s, 0, 0, 0);
        s = __builtin_amdgcn_mfma_f32_16x16x32_bf16(curK[h * 2 + 1], Qf1, s, 0, 0, 0);
        ST[h] = s;
    }

    const int q_g = qw + l15;
    float p[2][4];
    float mt = -INFINITY;
    if (k0 + FA_BK - 1 <= qw) {           // fully valid tile
        #pragma unroll
        for (int h = 0; h < 2; ++h)
            #pragma unroll
            for (int r = 0; r < 4; ++r) {
                float v = ST[h][r] * scale;
                p[h][r] = v;
                mt = fmaxf(mt, v);
            }
    } else {                               // diagonal tile: causal mask
        #pragma unroll
        for (int h = 0; h < 2; ++h)
            #pragma unroll
            for (int r = 0; r < 4; ++r) {
                int key_g = k0 + h * 16 + quad * 4 + r;
                float v = (key_g <= q_g) ? ST[h][r] * scale : -INFINITY;
                p[h][r] = v;
                mt = fmaxf(mt, v);
            }
    }
    mt = fmaxf(mt, __shfl_xor(mt, 16, 64));
    mt = fmaxf(mt, __shfl_xor(mt, 32, 64));
    float m_new = fmaxf(st.m_prev, mt);
    float alpha = __expf(st.m_prev - m_new);   // first tile: exp(-inf)=0
    float ls = 0.f;
    #pragma unroll
    for (int h = 0; h < 2; ++h)
        #pragma unroll
        for (int r = 0; r < 4; ++r) {
            float e = __expf(p[h][r] - m_new);
            p[h][r] = e;
            ls += e;
        }
    st.l_part = st.l_part * alpha + ls;    // per-lane partial (q=l15)
    st.m_prev = m_new;

    // P^T -> PT[q][key] (bf16), wave-private; packed b64 writes
    #pragma unroll
    for (int h = 0; h < 2; ++h) {
        ushort_t pk[4] = {f2bf(p[h][0]), f2bf(p[h][1]),
                          f2bf(p[h][2]), f2bf(p[h][3])};
        *(uint2*)&PTw[l15 * 40 + h * 16 + quad * 4] = *(const uint2*)pk;
    }

    // O rescale (alpha for q=quad*4+r via in-group broadcast)
    #pragma unroll
    for (int r = 0; r < 4; ++r) {
        float ar = __shfl(alpha, (lane & 48) + quad * 4 + r, 64);
        #pragma unroll
        for (int c = 0; c < 4; ++c) st.O[c][r] *= ar;
    }

    // PV: A = PT (m=q=l15, k=key=quad*8+j); B = V frag (k=key, n=d chunk)
    bfrag pA = *(const bfrag*)&PTw[l15 * 40 + quad * 8];
    #pragma unroll
    for (int c = 0; c < 4; ++c)
        st.O[c] = __builtin_amdgcn_mfma_f32_16x16x32_bf16(pA, curV[c], st.O[c], 0, 0, 0);
}

__global__ __launch_bounds__(256)
void flash_mfma(const ushort_t* __restrict__ Q, const ushort_t* __restrict__ K,
                const ushort_t* __restrict__ Vt, ushort_t* __restrict__ ctx)
{
    __shared__ ushort_t PT[4][16 * 40];     // per-wave [q][key], stride 40

    const int tid  = threadIdx.x;
    const int lane = tid & 63;
    const int w    = tid >> 6;
    // XCD-aware swizzle: blocks ≡ i (mod 8) share bh group i (4 bh, 2 MB K/V)
    const int bidx  = blockIdx.x;
    const int bh    = (bidx & 7) * 4 + ((bidx >> 3) & 3);
    const int qtile = 31 - (bidx >> 5);     // longest-first
    const int qw   = qtile * FA_BQ + w * 16;
    const int l15  = lane & 15;
    const int quad = lane >> 4;

    const ushort_t* Qrow = Q + ((size_t)bh * Sdim + qw + l15) * HDdim;
    bfrag Qf0 = *(const bfrag*)(Qrow + quad * 8);
    bfrag Qf1 = *(const bfrag*)(Qrow + 32 + quad * 8);

    const ushort_t* Kp = K  + (size_t)bh * Sdim * HDdim;
    const ushort_t* Vp = Vt + (size_t)bh * HDdim * Sdim;
    ushort_t* PTw = PT[w];

    FaState st;
    #pragma unroll
    for (int c = 0; c < 4; ++c) st.O[c] = (f4){0.f, 0.f, 0.f, 0.f};
    st.m_prev = -INFINITY;
    st.l_part = 0.f;

    const int ntiles = (qw + 16 + FA_BK - 1) / FA_BK;   // per-wave

    // preload tile 0
    bfrag KA[4], VA[4], KB[4], VB[4];
    #pragma unroll
    for (int h = 0; h < 2; ++h) {
        const ushort_t* kr = Kp + (size_t)(h * 16 + l15) * HDdim;
        KA[h * 2]     = *(const bfrag*)(kr + quad * 8);
        KA[h * 2 + 1] = *(const bfrag*)(kr + 32 + quad * 8);
    }
    #pragma unroll
    for (int c = 0; c < 4; ++c)
        VA[c] = *(const bfrag*)(Vp + (size_t)(c * 16 + l15) * Sdim + quad * 8);

    int kt = 0;
    while (true) {
        fa_tile(kt, ntiles, qw, l15, quad, lane, Kp, Vp, Qf0, Qf1,
                KA, VA, KB, VB, st, PTw);
        if (++kt >= ntiles) break;
        fa_tile(kt, ntiles, qw, l15, quad, lane, Kp, Vp, Qf0, Qf1,
                KB, VB, KA, VA, st, PTw);
        if (++kt >= ntiles) break;
    }

    // final l reduction (over quads) + epilogue: bf16 ctx [B,S,D]
    st.l_part += __shfl_xor(st.l_part, 16, 64);
    st.l_part += __shfl_xor(st.l_part, 32, 64);

    const int b = bh >> 4, h = bh & 15;
    #pragma unroll
    for (int r = 0; r < 4; ++r) {
        float inv_l = 1.0f / __shfl(st.l_part, (lane & 48) + quad * 4 + r, 64);
        size_t base = ((size_t)b * Sdim + qw + quad * 4 + r) * Ddim + h * HDdim + l15;
        #pragma unroll
        for (int c = 0; c < 4; ++c)
            ctx[base + c * 16] = f2bf(st.O[c][r] * inv_l);
    }
}

// ---------------- launch ----------------
extern "C" void kernel_launch(void* const* d_in, const int* in_sizes, int n_in,
                              void* d_out, int out_size, void* d_ws, size_t ws_size,
                              hipStream_t stream)
{
    const int NX = Mdim * Ddim;
    const int NW = Ddim * Ddim;
    int xi = 0, wi[4] = {1, 3, 5, 7}, bi[4] = {2, 4, 6, 8}, nw = 0, nb = 0;
    bool sized = true;
    for (int i = 0; i < 9; ++i) {
        if (in_sizes[i] == NX) xi = i;
        else if (in_sizes[i] == NW) { if (nw < 4) wi[nw++] = i; }
        else if (in_sizes[i] == Ddim) { if (nb < 4) bi[nb++] = i; }
        else sized = false;
    }
    int iWq, iWk, iWv, iWo, ibq, ibk, ibv, ibo;
    if (!sized || xi == 0) {
        xi = 0; iWq = 1; ibq = 2; iWk = 3; ibk = 4; iWv = 5; ibv = 6; iWo = 7; ibo = 8;
    } else {
        iWk = wi[0]; iWo = wi[1]; iWq = wi[2]; iWv = wi[3];
        ibk = bi[0]; ibo = bi[1]; ibq = bi[2]; ibv = bi[3];
    }

    const float* x  = (const float*)d_in[xi];
    const float* Wq = (const float*)d_in[iWq];
    const float* bq = (const float*)d_in[ibq];
    const float* Wk = (const float*)d_in[iWk];
    const float* bk = (const float*)d_in[ibk];
    const float* Wv = (const float*)d_in[iWv];
    const float* bv = (const float*)d_in[ibv];
    const float* Wo = (const float*)d_in[iWo];
    const float* bo = (const float*)d_in[ibo];
    float* out = (float*)d_out;

    const size_t elems = (size_t)Mdim * Ddim;
    const size_t welems = (size_t)Ddim * Ddim;
    ushort_t* Qb    = (ushort_t*)d_ws;
    ushort_t* Kb    = Qb + elems;
    ushort_t* Vtb   = Kb + elems;
    ushort_t* Cb    = Vtb + elems;
    ushort_t* xb    = Cb + elems;
    ushort_t* qkvT  = xb + elems;
    ushort_t* WoT   = qkvT + 3 * welems;

    dim3 blk(256);
    cast_x<<<dim3(Mdim * Ddim / (256 * 8)), blk, 0, stream>>>(x, xb);
    wtrans<<<dim3(16, 16, 4), blk, 0, stream>>>(Wq, Wk, Wv, Wo, qkvT, WoT);

    gemm_mfma<0><<<dim3(3 * Ddim / 128, Mdim / 128), blk, 0, stream>>>(
        xb, qkvT, bq, bk, bv, Qb, Kb, Vtb, nullptr);

    flash_mfma<<<dim3(32 * 32), blk, 0, stream>>>(Qb, Kb, Vtb, Cb);

    gemm_mfma<1><<<dim3(Ddim / 128, Mdim / 128), blk, 0, stream>>>(
        Cb, WoT, bo, nullptr, nullptr, nullptr, nullptr, nullptr, out);
}

// Round 10
// 260.271 us; speedup vs baseline: 1.0955x; 1.0955x over previous
//
#include <hip/hip_runtime.h>
#include <hip/hip_bf16.h>
#include <math.h>

// B=2, S=2048, D=1024, H=16, HD=64. Inputs fp32, output fp32.
// R10: flash attention = paired-q-tile, dual-stream, barrier-free.
// Block handles q-tiles p and 31-p (33 tile-pairs each -> zero tail).
// Each wave: two independent 16-row softmax streams sharing one K/V
// fragment sequence (8 global frag loads feed 16 MFMAs/tile); streams'
// dependency chains interleave for latency hiding. No in-loop barriers;
// PT round-trip in wave-private LDS. XCD swizzle: 4 bh per XCD L2.
// GEMMs (m97-style bf16 MFMA, fused QKV) unchanged from R7-R9.

#define Bdim  2
#define Sdim  2048
#define Ddim  1024
#define Hn    16
#define HDdim 64
#define Mdim  (Bdim * Sdim)   // 4096

typedef unsigned short ushort_t;
typedef __attribute__((ext_vector_type(8))) short bfrag;   // 8 bf16 (4 VGPR)
typedef __attribute__((ext_vector_type(4))) float f4;

__device__ __forceinline__ ushort_t f2bf(float f) {
    union { float f; unsigned int i; } c;
    c.f = f;
    unsigned int x = c.i;
    unsigned int r = (x + 0x7fffu + ((x >> 16) & 1u)) >> 16;  // RNE
    return (ushort_t)r;
}

__device__ __forceinline__ void glds16(const void* g, void* l) {
    __builtin_amdgcn_global_load_lds(
        (const __attribute__((address_space(1))) unsigned int*)g,
        (__attribute__((address_space(3))) unsigned int*)l, 16, 0, 0);
}

// ---------------- cast x: fp32 [M][K] -> bf16 same layout ----------------
__global__ __launch_bounds__(256)
void cast_x(const float* __restrict__ x, ushort_t* __restrict__ xb)
{
    size_t i = ((size_t)blockIdx.x * 256 + threadIdx.x) * 8;
    float4 a = *(const float4*)(x + i);
    float4 b = *(const float4*)(x + i + 4);
    ushort_t o[8] = {f2bf(a.x), f2bf(a.y), f2bf(a.z), f2bf(a.w),
                     f2bf(b.x), f2bf(b.y), f2bf(b.z), f2bf(b.w)};
    *(bfrag*)(xb + i) = *(const bfrag*)o;
}

// ------------- transpose-cast weights: W[k][n] fp32 -> Wt[n][k] bf16 -------
__global__ __launch_bounds__(256)
void wtrans(const float* __restrict__ W0, const float* __restrict__ W1,
            const float* __restrict__ W2, const float* __restrict__ W3,
            ushort_t* __restrict__ qkvT, ushort_t* __restrict__ oT)
{
    __shared__ ushort_t t[64][72];   // [n][k], padded
    const int tid = threadIdx.x;
    const int z = blockIdx.z;
    const float* W = (z == 0) ? W0 : (z == 1) ? W1 : (z == 2) ? W2 : W3;
    const int k0 = blockIdx.y * 64, n0 = blockIdx.x * 64;

    const int r = tid >> 4, c4 = (tid & 15) * 4;
    #pragma unroll
    for (int rr = 0; rr < 4; ++rr) {
        int k = r + rr * 16;
        float4 v = *(const float4*)&W[(size_t)(k0 + k) * Ddim + n0 + c4];
        t[c4 + 0][k] = f2bf(v.x);
        t[c4 + 1][k] = f2bf(v.y);
        t[c4 + 2][k] = f2bf(v.z);
        t[c4 + 3][k] = f2bf(v.w);
    }
    __syncthreads();
    ushort_t* out = (z < 3) ? (qkvT + (size_t)z * Ddim * Ddim) : oT;
    const int n = tid >> 2, kc = (tid & 3) * 16;
    *(bfrag*)&out[(size_t)(n0 + n) * Ddim + k0 + kc] = *(const bfrag*)&t[n][kc];
    *(bfrag*)&out[(size_t)(n0 + n) * Ddim + k0 + kc + 8] = *(const bfrag*)&t[n][kc + 8];
}

// ---------------- MFMA GEMM (m97 structure, NT) ----------------
// MODE 0: Ntot=3072 fused QKV; scatter bf16 to Q,K [B,H,S,HD], Vt [B,H,HD,S].
// MODE 1: Ntot=1024; fp32 out [M,N].
template <int MODE>
__global__ __launch_bounds__(256)
void gemm_mfma(const ushort_t* __restrict__ A, const ushort_t* __restrict__ Bt,
               const float* __restrict__ bQ, const float* __restrict__ bK,
               const float* __restrict__ bV,
               ushort_t* __restrict__ oQ, ushort_t* __restrict__ oK,
               ushort_t* __restrict__ oVt, float* __restrict__ oF)
{
    __shared__ ushort_t As[128 * 32];   // [row][k], 64 B rows
    __shared__ ushort_t Bs[128 * 32];

    const int tid  = threadIdx.x;
    const int lane = tid & 63;
    const int w    = tid >> 6;
    const int l15  = lane & 15;
    const int quad = lane >> 4;
    const int wr   = w >> 1, wc = w & 1;
    const int m0 = blockIdx.y * 128;
    const int n0 = blockIdx.x * 128;

    f4 acc[4][4];
    #pragma unroll
    for (int i = 0; i < 4; ++i)
        #pragma unroll
        for (int j = 0; j < 4; ++j) acc[i][j] = (f4){0.f, 0.f, 0.f, 0.f};

    const int srow  = w * 32 + (lane >> 2);
    const int selem = (lane & 3) * 8;
    const ushort_t* gA = A  + (size_t)(m0 + srow) * Ddim + selem;
    const ushort_t* gB = Bt + (size_t)(n0 + srow) * Ddim + selem;
    char* lA0 = (char*)As + (w * 32) * 64;
    char* lB0 = (char*)Bs + (w * 32) * 64;

    for (int kk = 0; kk < Ddim; kk += 32) {
        __syncthreads();
        glds16(gA + kk,              lA0);
        glds16(gA + 16 * Ddim + kk,  lA0 + 1024);
        glds16(gB + kk,              lB0);
        glds16(gB + 16 * Ddim + kk,  lB0 + 1024);
        __syncthreads();

        bfrag Af[4], Bf[4];
        #pragma unroll
        for (int i = 0; i < 4; ++i)
            Af[i] = *(const bfrag*)&As[(wr * 64 + i * 16 + l15) * 32 + quad * 8];
        #pragma unroll
        for (int j = 0; j < 4; ++j)
            Bf[j] = *(const bfrag*)&Bs[(wc * 64 + j * 16 + l15) * 32 + quad * 8];
        #pragma unroll
        for (int i = 0; i < 4; ++i)
            #pragma unroll
            for (int j = 0; j < 4; ++j)
                acc[i][j] = __builtin_amdgcn_mfma_f32_16x16x32_bf16(Af[i], Bf[j], acc[i][j], 0, 0, 0);
    }

    if constexpr (MODE == 0) {
        const int sel   = n0 >> 10;
        const int dbase = n0 & 1023;
        const float* bias = (sel == 0) ? bQ : (sel == 1) ? bK : bV;
        ushort_t* dst = (sel == 0) ? oQ : (sel == 1) ? oK : oVt;
        #pragma unroll
        for (int j = 0; j < 4; ++j) {
            int dn = dbase + wc * 64 + j * 16 + l15;
            float bv = bias[dn];
            int h = dn >> 6, e = dn & 63;
            #pragma unroll
            for (int i = 0; i < 4; ++i) {
                #pragma unroll
                for (int r = 0; r < 4; ++r) {
                    int m = m0 + wr * 64 + i * 16 + quad * 4 + r;
                    int b = m >> 11, s = m & 2047;
                    float v = acc[i][j][r] + bv;
                    if (sel < 2)
                        dst[((((size_t)b * Hn + h) * Sdim + s) << 6) + e] = f2bf(v);
                    else
                        dst[(((size_t)b * Hn + h) * HDdim + e) * Sdim + s] = f2bf(v);
                }
            }
        }
    } else {
        #pragma unroll
        for (int j = 0; j < 4; ++j) {
            int n = n0 + wc * 64 + j * 16 + l15;
            float bv = bQ[n];   // bo
            #pragma unroll
            for (int i = 0; i < 4; ++i)
                #pragma unroll
                for (int r = 0; r < 4; ++r) {
                    int m = m0 + wr * 64 + i * 16 + quad * 4 + r;
                    oF[(size_t)m * Ddim + n] = acc[i][j][r] + bv;
                }
        }
    }
}

// ------------- Flash attention: paired q-tiles, dual-stream, no barriers ---
#define FA_BK 32

struct FaState {
    f4 O[4];
    float m_prev;
    float l_part;
};

// one stream's QK -> softmax -> PV for the tile whose K/V frags are (curK,curV)
__device__ __forceinline__ void fa_stream(
    int k0, int qw, int l15, int quad, int lane,
    bfrag Qf0, bfrag Qf1, const bfrag* curK, const bfrag* curV,
    FaState& st, ushort_t* PTw)
{
    const float scale = 0.125f;

    f4 ST[2];
    #pragma unroll
    for (int h = 0; h < 2; ++h) {
        f4 s = (f4){0.f, 0.f, 0.f, 0.f};
        s = __builtin_amdgcn_mfma_f32_16x16x32_bf16(curK[h * 2],     Qf0, s, 0, 0, 0);
        s = __builtin_amdgcn_mfma_f32_16x16x32_bf16(curK[h * 2 + 1], Qf1, s, 0, 0, 0);
        ST[h] = s;
    }

    const int q_g = qw + l15;
    float p[2][4];
    float mt = -INFINITY;
    if (k0 + FA_BK - 1 <= qw) {           // fully valid tile
        #pragma unroll
        for (int h = 0; h < 2; ++h)
            #pragma unroll
            for (int r = 0; r < 4; ++r) {
                float v = ST[h][r] * scale;
                p[h][r] = v;
                mt = fmaxf(mt, v);
            }
    } else {                               // diagonal tile: causal mask
        #pragma unroll
        for (int h = 0; h < 2; ++h)
            #pragma unroll
            for (int r = 0; r < 4; ++r) {
                int key_g = k0 + h * 16 + quad * 4 + r;
                float v = (key_g <= q_g) ? ST[h][r] * scale : -INFINITY;
                p[h][r] = v;
                mt = fmaxf(mt, v);
            }
    }
    mt = fmaxf(mt, __shfl_xor(mt, 16, 64));
    mt = fmaxf(mt, __shfl_xor(mt, 32, 64));
    float m_new = fmaxf(st.m_prev, mt);
    float alpha = __expf(st.m_prev - m_new);   // first tile: exp(-inf)=0
    float ls = 0.f;
    #pragma unroll
    for (int h = 0; h < 2; ++h)
        #pragma unroll
        for (int r = 0; r < 4; ++r) {
            float e = __expf(p[h][r] - m_new);
            p[h][r] = e;
            ls += e;
        }
    st.l_part = st.l_part * alpha + ls;    // per-lane partial (q=l15)
    st.m_prev = m_new;

    // P^T -> PT[q][key] (bf16), wave-private; packed b64 writes
    #pragma unroll
    for (int h = 0; h < 2; ++h) {
        ushort_t pk[4] = {f2bf(p[h][0]), f2bf(p[h][1]),
                          f2bf(p[h][2]), f2bf(p[h][3])};
        *(uint2*)&PTw[l15 * 40 + h * 16 + quad * 4] = *(const uint2*)pk;
    }

    // O rescale (alpha for q=quad*4+r via in-group broadcast)
    #pragma unroll
    for (int r = 0; r < 4; ++r) {
        float ar = __shfl(alpha, (lane & 48) + quad * 4 + r, 64);
        #pragma unroll
        for (int c = 0; c < 4; ++c) st.O[c][r] *= ar;
    }

    // PV: A = PT (m=q=l15, k=key=quad*8+j); B = V frag (k=key, n=d chunk)
    bfrag pA = *(const bfrag*)&PTw[l15 * 40 + quad * 8];
    #pragma unroll
    for (int c = 0; c < 4; ++c)
        st.O[c] = __builtin_amdgcn_mfma_f32_16x16x32_bf16(pA, curV[c], st.O[c], 0, 0, 0);
}

// one tile: prefetch kt+1 frags, then run stream A (optional) and B
template <bool DO_A>
__device__ __forceinline__ void fa_tile(
    int kt, int ntB, int qwA, int qwB, int l15, int quad, int lane,
    const ushort_t* __restrict__ Kp, const ushort_t* __restrict__ Vp,
    bfrag QfA0, bfrag QfA1, bfrag QfB0, bfrag QfB1,
    bfrag* curK, bfrag* curV, bfrag* nxtK, bfrag* nxtV,
    FaState& stA, FaState& stB, ushort_t* PTa, ushort_t* PTb)
{
    const int k0 = kt * FA_BK;

    if (kt + 1 < ntB) {
        const int kn0 = k0 + FA_BK;
        #pragma unroll
        for (int h = 0; h < 2; ++h) {
            const ushort_t* kr = Kp + (size_t)(kn0 + h * 16 + l15) * HDdim;
            nxtK[h * 2]     = *(const bfrag*)(kr + quad * 8);
            nxtK[h * 2 + 1] = *(const bfrag*)(kr + 32 + quad * 8);
        }
        #pragma unroll
        for (int c = 0; c < 4; ++c)
            nxtV[c] = *(const bfrag*)(Vp + (size_t)(c * 16 + l15) * Sdim + kn0 + quad * 8);
    }

    if constexpr (DO_A)
        fa_stream(k0, qwA, l15, quad, lane, QfA0, QfA1, curK, curV, stA, PTa);
    fa_stream(k0, qwB, l15, quad, lane, QfB0, QfB1, curK, curV, stB, PTb);
}

__global__ __launch_bounds__(256)
void flash_mfma(const ushort_t* __restrict__ Q, const ushort_t* __restrict__ K,
                const ushort_t* __restrict__ Vt, ushort_t* __restrict__ ctx)
{
    __shared__ ushort_t PT[8][16 * 40];     // [wave*2+stream][q][key]

    const int tid  = threadIdx.x;
    const int lane = tid & 63;
    const int w    = tid >> 6;
    // 512 blocks: 16 pair-groups x 32 bh. XCD swizzle within each group of 32.
    const int bidx = blockIdx.x;
    const int bh   = (bidx & 7) * 4 + ((bidx >> 3) & 3);
    const int pA   = bidx >> 5;             // 0..15
    const int pB   = 31 - pA;               // complementary q-tile
    const int qwA  = pA * 64 + w * 16;
    const int qwB  = pB * 64 + w * 16;
    const int l15  = lane & 15;
    const int quad = lane >> 4;

    const ushort_t* QrowA = Q + ((size_t)bh * Sdim + qwA + l15) * HDdim;
    const ushort_t* QrowB = Q + ((size_t)bh * Sdim + qwB + l15) * HDdim;
    bfrag QfA0 = *(const bfrag*)(QrowA + quad * 8);
    bfrag QfA1 = *(const bfrag*)(QrowA + 32 + quad * 8);
    bfrag QfB0 = *(const bfrag*)(QrowB + quad * 8);
    bfrag QfB1 = *(const bfrag*)(QrowB + 32 + quad * 8);

    const ushort_t* Kp = K  + (size_t)bh * Sdim * HDdim;
    const ushort_t* Vp = Vt + (size_t)bh * HDdim * Sdim;
    ushort_t* PTa = PT[w * 2];
    ushort_t* PTb = PT[w * 2 + 1];

    FaState stA, stB;
    #pragma unroll
    for (int c = 0; c < 4; ++c) { stA.O[c] = (f4){0.f,0.f,0.f,0.f}; stB.O[c] = (f4){0.f,0.f,0.f,0.f}; }
    stA.m_prev = -INFINITY; stA.l_part = 0.f;
    stB.m_prev = -INFINITY; stB.l_part = 0.f;

    const int ntA = (qwA + 47) / FA_BK;     // tiles for stream A
    const int ntB = (qwB + 47) / FA_BK;     // tiles for stream B (ntB > ntA)

    // preload tile 0
    bfrag KA[4], VA[4], KB[4], VB[4];
    #pragma unroll
    for (int h = 0; h < 2; ++h) {
        const ushort_t* kr = Kp + (size_t)(h * 16 + l15) * HDdim;
        KA[h * 2]     = *(const bfrag*)(kr + quad * 8);
        KA[h * 2 + 1] = *(const bfrag*)(kr + 32 + quad * 8);
    }
    #pragma unroll
    for (int c = 0; c < 4; ++c)
        VA[c] = *(const bfrag*)(Vp + (size_t)(c * 16 + l15) * Sdim + quad * 8);

    // joint region: both streams, shared K/V frags (tile kt even -> KA/VA)
    int kt = 0;
    while (true) {
        fa_tile<true>(kt, ntB, qwA, qwB, l15, quad, lane, Kp, Vp,
                      QfA0, QfA1, QfB0, QfB1, KA, VA, KB, VB, stA, stB, PTa, PTb);
        if (++kt >= ntA) break;
        fa_tile<true>(kt, ntB, qwA, qwB, l15, quad, lane, Kp, Vp,
                      QfA0, QfA1, QfB0, QfB1, KB, VB, KA, VA, stA, stB, PTa, PTb);
        if (++kt >= ntA) break;
    }
    // parity fix, then B-only region
    if (kt < ntB && (kt & 1)) {
        fa_tile<false>(kt, ntB, qwA, qwB, l15, quad, lane, Kp, Vp,
                       QfA0, QfA1, QfB0, QfB1, KB, VB, KA, VA, stA, stB, PTa, PTb);
        ++kt;
    }
    while (kt < ntB) {
        fa_tile<false>(kt, ntB, qwA, qwB, l15, quad, lane, Kp, Vp,
                       QfA0, QfA1, QfB0, QfB1, KA, VA, KB, VB, stA, stB, PTa, PTb);
        if (++kt >= ntB) break;
        fa_tile<false>(kt, ntB, qwA, qwB, l15, quad, lane, Kp, Vp,
                       QfA0, QfA1, QfB0, QfB1, KB, VB, KA, VA, stA, stB, PTa, PTb);
        if (++kt >= ntB) break;
    }

    // final l reductions + epilogue (bf16 ctx [B,S,D]) for both streams
    stA.l_part += __shfl_xor(stA.l_part, 16, 64);
    stA.l_part += __shfl_xor(stA.l_part, 32, 64);
    stB.l_part += __shfl_xor(stB.l_part, 16, 64);
    stB.l_part += __shfl_xor(stB.l_part, 32, 64);

    const int b = bh >> 4, h = bh & 15;
    #pragma unroll
    for (int r = 0; r < 4; ++r) {
        float invA = 1.0f / __shfl(stA.l_part, (lane & 48) + quad * 4 + r, 64);
        float invB = 1.0f / __shfl(stB.l_part, (lane & 48) + quad * 4 + r, 64);
        size_t baseA = ((size_t)b * Sdim + qwA + quad * 4 + r) * Ddim + h * HDdim + l15;
        size_t baseB = ((size_t)b * Sdim + qwB + quad * 4 + r) * Ddim + h * HDdim + l15;
        #pragma unroll
        for (int c = 0; c < 4; ++c) {
            ctx[baseA + c * 16] = f2bf(stA.O[c][r] * invA);
            ctx[baseB + c * 16] = f2bf(stB.O[c][r] * invB);
        }
    }
}

// ---------------- launch ----------------
extern "C" void kernel_launch(void* const* d_in, const int* in_sizes, int n_in,
                              void* d_out, int out_size, void* d_ws, size_t ws_size,
                              hipStream_t stream)
{
    const int NX = Mdim * Ddim;
    const int NW = Ddim * Ddim;
    int xi = 0, wi[4] = {1, 3, 5, 7}, bi[4] = {2, 4, 6, 8}, nw = 0, nb = 0;
    bool sized = true;
    for (int i = 0; i < 9; ++i) {
        if (in_sizes[i] == NX) xi = i;
        else if (in_sizes[i] == NW) { if (nw < 4) wi[nw++] = i; }
        else if (in_sizes[i] == Ddim) { if (nb < 4) bi[nb++] = i; }
        else sized = false;
    }
    int iWq, iWk, iWv, iWo, ibq, ibk, ibv, ibo;
    if (!sized || xi == 0) {
        xi = 0; iWq = 1; ibq = 2; iWk = 3; ibk = 4; iWv = 5; ibv = 6; iWo = 7; ibo = 8;
    } else {
        iWk = wi[0]; iWo = wi[1]; iWq = wi[2]; iWv = wi[3];
        ibk = bi[0]; ibo = bi[1]; ibq = bi[2]; ibv = bi[3];
    }

    const float* x  = (const float*)d_in[xi];
    const float* Wq = (const float*)d_in[iWq];
    const float* bq = (const float*)d_in[ibq];
    const float* Wk = (const float*)d_in[iWk];
    const float* bk = (const float*)d_in[ibk];
    const float* Wv = (const float*)d_in[iWv];
    const float* bv = (const float*)d_in[ibv];
    const float* Wo = (const float*)d_in[iWo];
    const float* bo = (const float*)d_in[ibo];
    float* out = (float*)d_out;

    const size_t elems = (size_t)Mdim * Ddim;
    const size_t welems = (size_t)Ddim * Ddim;
    ushort_t* Qb    = (ushort_t*)d_ws;
    ushort_t* Kb    = Qb + elems;
    ushort_t* Vtb   = Kb + elems;
    ushort_t* Cb    = Vtb + elems;
    ushort_t* xb    = Cb + elems;
    ushort_t* qkvT  = xb + elems;
    ushort_t* WoT   = qkvT + 3 * welems;

    dim3 blk(256);
    cast_x<<<dim3(Mdim * Ddim / (256 * 8)), blk, 0, stream>>>(x, xb);
    wtrans<<<dim3(16, 16, 4), blk, 0, stream>>>(Wq, Wk, Wv, Wo, qkvT, WoT);

    gemm_mfma<0><<<dim3(3 * Ddim / 128, Mdim / 128), blk, 0, stream>>>(
        xb, qkvT, bq, bk, bv, Qb, Kb, Vtb, nullptr);

    flash_mfma<<<dim3(512), blk, 0, stream>>>(Qb, Kb, Vtb, Cb);

    gemm_mfma<1><<<dim3(Ddim / 128, Mdim / 128), blk, 0, stream>>>(
        Cb, WoT, bo, nullptr, nullptr, nullptr, nullptr, nullptr, out);
}